// Round 8
// baseline (267.802 us; speedup 1.0000x reference)
//
#include <hip/hip_runtime.h>
#include <stdint.h>

typedef short short8 __attribute__((ext_vector_type(8)));
typedef float f32x4 __attribute__((ext_vector_type(4)));

#define D 128
#define LOG2E 1.44269504088896340736f
#define GPB 4   // graphs per block (grid = B/GPB)

__device__ __forceinline__ unsigned short f2bf(float f) {
    union { float f; unsigned u; } v; v.f = f;
    unsigned u = v.u;
    unsigned r = (u + 0x7FFFu + ((u >> 16) & 1u)) >> 16;  // RNE
    return (unsigned short)r;
}

// pack two f32 -> one u32 of two bf16 (round-half-up via +0x8000, then v_perm)
__device__ __forceinline__ unsigned packbf(float x, float y) {
    unsigned ux = __float_as_uint(x) + 0x8000u;
    unsigned uy = __float_as_uint(y) + 0x8000u;
    return __builtin_amdgcn_perm(uy, ux, 0x07060302u);
}

// DPP butterfly add within 16-lane groups (verified rounds 5-7).
template <int C>
__device__ __forceinline__ float dpp_add(float x) {
    int y = __builtin_amdgcn_update_dpp(0, __float_as_int(x), C, 0xF, 0xF, true);
    return x + __int_as_float(y);
}
__device__ __forceinline__ float red16(float x) {
    x = dpp_add<0xB1>(x);
    x = dpp_add<0x4E>(x);
    x = dpp_add<0x141>(x);
    x = dpp_add<0x140>(x);
    return x;
}

// ---------------------------------------------------------------------------
// Kernel 1: pre-pack (Wu * log2e) as bf16 MFMA B-fragments.
// t = nt*256 + kk*64 + lane holds B[k][col], col = nt*16+(lane&15),
// k = kk*32+(lane>>4)*8+j  (B[k][col] = Wu[col][k], u = f @ Wu^T)
// ---------------------------------------------------------------------------
__global__ __launch_bounds__(256) void pack_wu(const float* __restrict__ Wu,
                                               short8* __restrict__ frag) {
    int tid = blockIdx.x * 256 + threadIdx.x;
    int nt = tid >> 8, kk = (tid >> 6) & 3, l = tid & 63;
    int col = nt * 16 + (l & 15);
    int kb  = kk * 32 + ((l >> 4) * 8);
    short8 o;
#pragma unroll
    for (int j = 0; j < 8; ++j) o[j] = (short)f2bf(Wu[col * D + kb + j] * LOG2E);
    frag[tid] = o;
}

// ---------------------------------------------------------------------------
// Kernel 2: per-graph gate factors  c = 2^{-(Wv·x_last + bu)·log2e}.
// 16 graphs per block; Wv stays L1/L2-hot. (Validated round 5.)
// ---------------------------------------------------------------------------
__global__ __launch_bounds__(256) void gate_k(const float* __restrict__ xI,
                                              const float* __restrict__ xV,
                                              const float* __restrict__ Wv,
                                              const float* __restrict__ bu,
                                              const int* __restrict__ lastn,
                                              float* __restrict__ cIb,
                                              float* __restrict__ cVb, int B) {
    __shared__ __align__(16) float xs[4][2][D];
    int t = threadIdx.x, h = t & 127, st = t >> 7;
    float bias = bu[h];
    const float4* wv4 = (const float4*)(Wv + (size_t)h * D);
    const float* src = st ? xV : xI;
    float* dst = st ? cVb : cIb;
    int g0 = blockIdx.x * 16;
    for (int p = 0; p < 4; ++p) {
        int gb = g0 + p * 4;
#pragma unroll
        for (int j = 0; j < 4; ++j) {
            int gg = gb + j; if (gg >= B) gg = B - 1;
            xs[j][st][h] = src[(size_t)lastn[gg] * D + h];
        }
        __syncthreads();
        const float4* x0 = (const float4*)xs[0][st];
        const float4* x1 = (const float4*)xs[1][st];
        const float4* x2 = (const float4*)xs[2][st];
        const float4* x3 = (const float4*)xs[3][st];
        float a0 = 0.f, a1 = 0.f, a2 = 0.f, a3 = 0.f;
#pragma unroll
        for (int i = 0; i < 32; ++i) {
            float4 w = wv4[i], b;
            b = x0[i]; a0 += w.x*b.x + w.y*b.y + w.z*b.z + w.w*b.w;
            b = x1[i]; a1 += w.x*b.x + w.y*b.y + w.z*b.z + w.w*b.w;
            b = x2[i]; a2 += w.x*b.x + w.y*b.y + w.z*b.z + w.w*b.w;
            b = x3[i]; a3 += w.x*b.x + w.y*b.y + w.z*b.z + w.w*b.w;
        }
        if (gb + 0 < B) dst[(size_t)(gb+0)*D + h] = __builtin_amdgcn_exp2f(-(a0+bias)*LOG2E);
        if (gb + 1 < B) dst[(size_t)(gb+1)*D + h] = __builtin_amdgcn_exp2f(-(a1+bias)*LOG2E);
        if (gb + 2 < B) dst[(size_t)(gb+2)*D + h] = __builtin_amdgcn_exp2f(-(a2+bias)*LOG2E);
        if (gb + 3 < B) dst[(size_t)(gb+3)*D + h] = __builtin_amdgcn_exp2f(-(a3+bias)*LOG2E);
        __syncthreads();
    }
}

// ---------------------------------------------------------------------------
// Kernel 3: fused main. GPB graphs per block; bfrag staged once. Per graph:
// 4 waves stride 16-row chunks. In-wave software pipeline:
//   pack af from pre (loaded last iter) | issue fr row-loads for this chunk
//   | issue pre gathers for chunk c+4 | MFMA+epilogue | softmax | accumulate
// so gather latency hides under the previous chunk's compute and the
// accumulate operands arrive during MFMA/epilogue. No memory clobber.
// ---------------------------------------------------------------------------
__global__ __launch_bounds__(256) void attn_main(
    const float* __restrict__ xI, const float* __restrict__ xV,
    const float* __restrict__ We, const int* __restrict__ lastn,
    const float* __restrict__ cIb, const float* __restrict__ cVb,
    const short8* __restrict__ fragG, float* __restrict__ out, int B) {
    __shared__ short8 bfrag[2048];                // 32 KB Wu fragments
    __shared__ __align__(16) float wt[4][16][2];  // per-wave weight table
    __shared__ float cmbA[2][4][D];               // combine
    __shared__ float cmbM[2][4], cmbL[2][4];

    int t = threadIdx.x, lane = t & 63, w = t >> 6;

    {   // stage Wu fragments once per block (contiguous 16B/lane)
        const uint4* srcf = (const uint4*)fragG;
        uint4* dst = (uint4*)bfrag;
#pragma unroll
        for (int i = 0; i < 8; ++i) dst[i * 256 + t] = srcf[i * 256 + t];
    }
    float WeR[8];                                 // graph-independent
#pragma unroll
    for (int nt = 0; nt < 8; ++nt) WeR[nt] = We[nt * 16 + (lane & 15)] * LOG2E;
    __syncthreads();

    int g0 = blockIdx.x * GPB;
    int sNext = (g0 == 0) ? 0 : (lastn[g0 - 1] + 1);

    for (int gi = 0; gi < GPB; ++gi) {
        int g = g0 + gi;
        int s = sNext;
        int e = lastn[g] + 1;
        sNext = e;
        int n = e - s;                            // >= 1

        float cIr[8], cVr[8];
#pragma unroll
        for (int nt = 0; nt < 8; ++nt) {
            int col = nt * 16 + (lane & 15);
            cIr[nt] = cIb[(size_t)g * D + col];
            cVr[nt] = cVb[(size_t)g * D + col];
        }

        float mI = -__builtin_inff(), mV = -__builtin_inff();
        float lIs = 0.f, lVs = 0.f;
        float aI0 = 0.f, aI1 = 0.f, aV0 = 0.f, aV1 = 0.f;

        int ch = (n + 15) >> 4;
        int total = 2 * ch;

        float4 pre[8];    // prefetched raw gather data for the NEXT chunk
        auto issuePre = [&](int cc) {
            int hf = (cc >= ch) ? 1 : 0;
            const float* sp = (hf ? xV : xI) + ((size_t)s << 7);
            int bb = (cc - hf * ch) << 4;
            int ar = bb + (lane & 15); if (ar > n - 1) ar = n - 1;
            const float* rp = sp + ((size_t)ar << 7) + ((lane >> 4) << 3);
#pragma unroll
            for (int kk = 0; kk < 4; ++kk) {
                pre[2 * kk]     = *(const float4*)(rp + kk * 32);
                pre[2 * kk + 1] = *(const float4*)(rp + kk * 32 + 4);
            }
        };

        if (w < total) issuePre(w);

        for (int c = w; c < total; c += 4) {
            int hf = (c >= ch) ? 1 : 0;
            const float* srcs = (hf ? xV : xI) + ((size_t)s << 7);
            int base = (c - hf * ch) << 4;

            // ---- pack A fragments from prefetched regs ----
            short8 af[4];
#pragma unroll
            for (int kk = 0; kk < 4; ++kk) {
                float4 f0 = pre[2 * kk], f1 = pre[2 * kk + 1];
                union { unsigned u[4]; short8 s8; } cv;
                cv.u[0] = packbf(f0.x, f0.y);
                cv.u[1] = packbf(f0.z, f0.w);
                cv.u[2] = packbf(f1.x, f1.y);
                cv.u[3] = packbf(f1.z, f1.w);
                af[kk] = cv.s8;
            }

            // ---- issue accumulate row-loads for THIS chunk (L1/L2-hot;
            //      consumed at the end, latency hidden by MFMA+epilogue) ----
            const float2* s2 = (const float2*)srcs;
            float2 fr[16];
#pragma unroll
            for (int r = 0; r < 16; ++r) {
                int rr = base + r; if (rr > n - 1) rr = n - 1;
                fr[r] = s2[((size_t)rr << 6) + lane];
            }

            // ---- issue next chunk's gathers (hidden by compute below) ----
            if (c + 4 < total) issuePre(c + 4);

            // ---- GEMM + gate epilogue (shared exp2 + shared rcp) ----
            float pI[4] = {0.f, 0.f, 0.f, 0.f}, pV[4] = {0.f, 0.f, 0.f, 0.f};
#pragma unroll
            for (int nt = 0; nt < 8; ++nt) {
                f32x4 dacc = {0.f, 0.f, 0.f, 0.f};
#pragma unroll
                for (int kk = 0; kk < 4; ++kk)
                    dacc = __builtin_amdgcn_mfma_f32_16x16x32_bf16(
                        af[kk], bfrag[nt * 256 + kk * 64 + lane], dacc, 0, 0, 0);
#pragma unroll
                for (int q = 0; q < 4; ++q) {
                    float t2 = __builtin_amdgcn_exp2f(-dacc[q]);
                    float dI = fmaf(t2, cIr[nt], 1.f);
                    float dV = fmaf(t2, cVr[nt], 1.f);
                    float rr = __builtin_amdgcn_rcpf(dI * dV);
                    pI[q] = fmaf(WeR[nt], dV * rr, pI[q]);   // WeR/dI
                    pV[q] = fmaf(WeR[nt], dI * rr, pV[q]);   // WeR/dV
                }
            }
            // reduce across 16 lanes via DPP; mask invalid rows (tail only)
#pragma unroll
            for (int q = 0; q < 4; ++q) { pI[q] = red16(pI[q]); pV[q] = red16(pV[q]); }
            if (base + 16 > n) {
#pragma unroll
                for (int q = 0; q < 4; ++q) {
                    int r = ((lane >> 4) << 2) + q;
                    if (base + r >= n) { pI[q] = -__builtin_inff(); pV[q] = -__builtin_inff(); }
                }
            }
            float cmI = fmaxf(fmaxf(pI[0], pI[1]), fmaxf(pI[2], pI[3]));
            float cmV = fmaxf(fmaxf(pV[0], pV[1]), fmaxf(pV[2], pV[3]));
            cmI = fmaxf(cmI, __shfl_xor(cmI, 16)); cmI = fmaxf(cmI, __shfl_xor(cmI, 32));
            cmV = fmaxf(cmV, __shfl_xor(cmV, 16)); cmV = fmaxf(cmV, __shfl_xor(cmV, 32));

            float mnI = fmaxf(mI, cmI), mnV = fmaxf(mV, cmV);
            float scI = __builtin_amdgcn_exp2f(mI - mnI);
            float scV = __builtin_amdgcn_exp2f(mV - mnV);
            lIs *= scI; lVs *= scV;
            aI0 *= scI; aI1 *= scI; aV0 *= scV; aV1 *= scV;

            float wIq[4], wVq[4];
#pragma unroll
            for (int q = 0; q < 4; ++q) {
                wIq[q] = __builtin_amdgcn_exp2f(pI[q] - mnI);   // 0 for masked
                wVq[q] = __builtin_amdgcn_exp2f(pV[q] - mnV);
            }
            float sIq = wIq[0] + wIq[1] + wIq[2] + wIq[3];
            float sVq = wVq[0] + wVq[1] + wVq[2] + wVq[3];
            sIq += __shfl_xor(sIq, 16); sIq += __shfl_xor(sIq, 32);
            sVq += __shfl_xor(sVq, 16); sVq += __shfl_xor(sVq, 32);
            lIs += sIq; lVs += sVq;

            // publish weights to per-wave LDS table (same-wave DS ordering;
            // compiler keeps store->load order for may-alias LDS)
            if ((lane & 15) == 0) {
                int gq = lane >> 4;
                float4 w0 = {wIq[0], wVq[0], wIq[1], wVq[1]};
                float4 w1 = {wIq[2], wVq[2], wIq[3], wVq[3]};
                *(float4*)&wt[w][gq * 4 + 0][0] = w0;
                *(float4*)&wt[w][gq * 4 + 2][0] = w1;
            }

            // ---- weighted accumulate on prefetched fr regs ----
#pragma unroll
            for (int r = 0; r < 16; ++r) {
                float2 f = fr[r];
                float2 wv = *(const float2*)&wt[w][r][0];
                aI0 = fmaf(wv.x, f.x, aI0); aI1 = fmaf(wv.x, f.y, aI1);
                aV0 = fmaf(wv.y, f.x, aV0); aV1 = fmaf(wv.y, f.y, aV1);
            }
            mI = mnI; mV = mnV;
        }

        // ---- cross-wave flash combine (dims 2*lane, 2*lane+1) ----
        __syncthreads();   // WAR: previous graph's combine reads done
        {
            float2 vI = {aI0, aI1}, vV = {aV0, aV1};
            *(float2*)&cmbA[0][w][lane * 2] = vI;
            *(float2*)&cmbA[1][w][lane * 2] = vV;
        }
        if (lane == 0) {
            cmbM[0][w] = mI; cmbL[0][w] = lIs;
            cmbM[1][w] = mV; cmbL[1][w] = lVs;
        }
        __syncthreads();
        {
            int st = t >> 7, d = t & 127;
            float M = fmaxf(fmaxf(cmbM[st][0], cmbM[st][1]),
                            fmaxf(cmbM[st][2], cmbM[st][3]));
            float Ls = 0.f, A = 0.f;
#pragma unroll
            for (int ww = 0; ww < 4; ++ww) {
                float e2 = __builtin_amdgcn_exp2f(cmbM[st][ww] - M);  // 0 if idle
                Ls += cmbL[st][ww] * e2;
                A  += cmbA[st][ww][d] * e2;
            }
            out[(size_t)st * B * D + (size_t)g * D + d] = A * __builtin_amdgcn_rcpf(Ls);
        }
    }
}

// ---------------------------------------------------------------------------
extern "C" void kernel_launch(void* const* d_in, const int* in_sizes, int n_in,
                              void* d_out, int out_size, void* d_ws, size_t ws_size,
                              hipStream_t stream) {
    const float* xI    = (const float*)d_in[0];
    const float* xV    = (const float*)d_in[1];
    const float* Wu    = (const float*)d_in[2];
    const float* bu    = (const float*)d_in[3];
    const float* Wv    = (const float*)d_in[4];
    const float* We    = (const float*)d_in[5];
    // d_in[6] = seg_ids (unused: segments contiguous, last_nodes suffices)
    const int*   lastn = (const int*)d_in[7];
    const int B = in_sizes[7];               // 8192

    float*  cIb   = (float*)d_ws;
    float*  cVb   = cIb + (size_t)B * D;
    short8* fragW = (short8*)(cVb + (size_t)B * D);

    pack_wu<<<8, 256, 0, stream>>>(Wu, fragW);
    gate_k<<<(B + 15) / 16, 256, 0, stream>>>(xI, xV, Wv, bu, lastn, cIb, cVb, B);
    attn_main<<<B / GPB, 256, 0, stream>>>(xI, xV, We, lastn, cIb, cVb, fragW,
                                           (float*)d_out, B);
}

// Round 9
// 250.376 us; speedup vs baseline: 1.0696x; 1.0696x over previous
//
#include <hip/hip_runtime.h>
#include <stdint.h>

typedef short short8 __attribute__((ext_vector_type(8)));
typedef float f32x4 __attribute__((ext_vector_type(4)));

#define D 128
#define LOG2E 1.44269504088896340736f
#define GPB 4   // graphs per block (grid = B/GPB)

__device__ __forceinline__ unsigned short f2bf(float f) {
    union { float f; unsigned u; } v; v.f = f;
    unsigned u = v.u;
    unsigned r = (u + 0x7FFFu + ((u >> 16) & 1u)) >> 16;  // RNE
    return (unsigned short)r;
}

// pack two f32 -> one u32 of two bf16 (round-half-up via +0x8000, then v_perm)
__device__ __forceinline__ unsigned packbf(float x, float y) {
    unsigned ux = __float_as_uint(x) + 0x8000u;
    unsigned uy = __float_as_uint(y) + 0x8000u;
    return __builtin_amdgcn_perm(uy, ux, 0x07060302u);
}

// DPP butterfly add within 16-lane groups (verified rounds 5-8).
template <int C>
__device__ __forceinline__ float dpp_add(float x) {
    int y = __builtin_amdgcn_update_dpp(0, __float_as_int(x), C, 0xF, 0xF, true);
    return x + __int_as_float(y);
}
__device__ __forceinline__ float red16(float x) {
    x = dpp_add<0xB1>(x);
    x = dpp_add<0x4E>(x);
    x = dpp_add<0x141>(x);
    x = dpp_add<0x140>(x);
    return x;
}

// ---------------------------------------------------------------------------
// Kernel 1: pre-pack (Wu * log2e) as bf16 MFMA B-fragments.
// t = nt*256 + kk*64 + lane holds B[k][col], col = nt*16+(lane&15),
// k = kk*32+(lane>>4)*8+j  (B[k][col] = Wu[col][k], u = f @ Wu^T)
// ---------------------------------------------------------------------------
__global__ __launch_bounds__(256) void pack_wu(const float* __restrict__ Wu,
                                               short8* __restrict__ frag) {
    int tid = blockIdx.x * 256 + threadIdx.x;
    int nt = tid >> 8, kk = (tid >> 6) & 3, l = tid & 63;
    int col = nt * 16 + (l & 15);
    int kb  = kk * 32 + ((l >> 4) * 8);
    short8 o;
#pragma unroll
    for (int j = 0; j < 8; ++j) o[j] = (short)f2bf(Wu[col * D + kb + j] * LOG2E);
    frag[tid] = o;
}

// ---------------------------------------------------------------------------
// Kernel 2: per-graph gate factors  c = 2^{-(Wv·x_last + bu)·log2e}.
// 16 graphs per block; Wv stays L1/L2-hot. (Validated round 5.)
// ---------------------------------------------------------------------------
__global__ __launch_bounds__(256) void gate_k(const float* __restrict__ xI,
                                              const float* __restrict__ xV,
                                              const float* __restrict__ Wv,
                                              const float* __restrict__ bu,
                                              const int* __restrict__ lastn,
                                              float* __restrict__ cIb,
                                              float* __restrict__ cVb, int B) {
    __shared__ __align__(16) float xs[4][2][D];
    int t = threadIdx.x, h = t & 127, st = t >> 7;
    float bias = bu[h];
    const float4* wv4 = (const float4*)(Wv + (size_t)h * D);
    const float* src = st ? xV : xI;
    float* dst = st ? cVb : cIb;
    int g0 = blockIdx.x * 16;
    for (int p = 0; p < 4; ++p) {
        int gb = g0 + p * 4;
#pragma unroll
        for (int j = 0; j < 4; ++j) {
            int gg = gb + j; if (gg >= B) gg = B - 1;
            xs[j][st][h] = src[(size_t)lastn[gg] * D + h];
        }
        __syncthreads();
        const float4* x0 = (const float4*)xs[0][st];
        const float4* x1 = (const float4*)xs[1][st];
        const float4* x2 = (const float4*)xs[2][st];
        const float4* x3 = (const float4*)xs[3][st];
        float a0 = 0.f, a1 = 0.f, a2 = 0.f, a3 = 0.f;
#pragma unroll
        for (int i = 0; i < 32; ++i) {
            float4 w = wv4[i], b;
            b = x0[i]; a0 += w.x*b.x + w.y*b.y + w.z*b.z + w.w*b.w;
            b = x1[i]; a1 += w.x*b.x + w.y*b.y + w.z*b.z + w.w*b.w;
            b = x2[i]; a2 += w.x*b.x + w.y*b.y + w.z*b.z + w.w*b.w;
            b = x3[i]; a3 += w.x*b.x + w.y*b.y + w.z*b.z + w.w*b.w;
        }
        if (gb + 0 < B) dst[(size_t)(gb+0)*D + h] = __builtin_amdgcn_exp2f(-(a0+bias)*LOG2E);
        if (gb + 1 < B) dst[(size_t)(gb+1)*D + h] = __builtin_amdgcn_exp2f(-(a1+bias)*LOG2E);
        if (gb + 2 < B) dst[(size_t)(gb+2)*D + h] = __builtin_amdgcn_exp2f(-(a2+bias)*LOG2E);
        if (gb + 3 < B) dst[(size_t)(gb+3)*D + h] = __builtin_amdgcn_exp2f(-(a3+bias)*LOG2E);
        __syncthreads();
    }
}

// ---------------------------------------------------------------------------
// Kernel 3: fused main. GPB graphs per block; bfrag staged once. 4 waves
// stride 16-row chunks per graph. NO ONLINE MAX: e (log2 units) is bounded
// by ||We||_1 * log2e ~ 13 => direct 2^e accumulation is overflow-safe and
// removes the serial rescale dependency between chunks.
// Pipeline: pack af from pre -> issue pre for c+4 (the only cold-HBM reads)
// -> MFMA+epilogue -> fr row-loads (L1-hot) -> softmax weights -> accumulate.
// ---------------------------------------------------------------------------
__global__ __launch_bounds__(256) void attn_main(
    const float* __restrict__ xI, const float* __restrict__ xV,
    const float* __restrict__ We, const int* __restrict__ lastn,
    const float* __restrict__ cIb, const float* __restrict__ cVb,
    const short8* __restrict__ fragG, float* __restrict__ out, int B) {
    __shared__ short8 bfrag[2048];                // 32 KB Wu fragments
    __shared__ __align__(16) float wt[4][16][2];  // per-wave weight table
    __shared__ float cmbA[2][4][D];               // combine
    __shared__ float cmbL[2][4];

    int t = threadIdx.x, lane = t & 63, w = t >> 6;

    {   // stage Wu fragments once per block (contiguous 16B/lane)
        const uint4* srcf = (const uint4*)fragG;
        uint4* dst = (uint4*)bfrag;
#pragma unroll
        for (int i = 0; i < 8; ++i) dst[i * 256 + t] = srcf[i * 256 + t];
    }
    float WeR[8];                                 // graph-independent
#pragma unroll
    for (int nt = 0; nt < 8; ++nt) WeR[nt] = We[nt * 16 + (lane & 15)] * LOG2E;
    __syncthreads();

    int g0 = blockIdx.x * GPB;
    int sNext = (g0 == 0) ? 0 : (lastn[g0 - 1] + 1);

    for (int gi = 0; gi < GPB; ++gi) {
        int g = g0 + gi;
        int s = sNext;
        int e = lastn[g] + 1;
        sNext = e;
        int n = e - s;                            // >= 1

        float cIr[8], cVr[8];
#pragma unroll
        for (int nt = 0; nt < 8; ++nt) {
            int col = nt * 16 + (lane & 15);
            cIr[nt] = cIb[(size_t)g * D + col];
            cVr[nt] = cVb[(size_t)g * D + col];
        }

        float lIs = 0.f, lVs = 0.f;               // lane-local (quarter rows)
        float aI0 = 0.f, aI1 = 0.f, aV0 = 0.f, aV1 = 0.f;

        int ch = (n + 15) >> 4;
        int total = 2 * ch;

        float4 pre[8];    // prefetched gather data (cold HBM reads)
        auto issuePre = [&](int cc) {
            int hf = (cc >= ch) ? 1 : 0;
            const float* sp = (hf ? xV : xI) + ((size_t)s << 7);
            int bb = (cc - hf * ch) << 4;
            int ar = bb + (lane & 15); if (ar > n - 1) ar = n - 1;
            const float* rp = sp + ((size_t)ar << 7) + ((lane >> 4) << 3);
#pragma unroll
            for (int kk = 0; kk < 4; ++kk) {
                pre[2 * kk]     = *(const float4*)(rp + kk * 32);
                pre[2 * kk + 1] = *(const float4*)(rp + kk * 32 + 4);
            }
        };

        if (w < total) issuePre(w);

        for (int c = w; c < total; c += 4) {
            int hf = (c >= ch) ? 1 : 0;
            const float* srcs = (hf ? xV : xI) + ((size_t)s << 7);
            int base = (c - hf * ch) << 4;

            // ---- pack A fragments from prefetched regs (pre dead after) --
            short8 af[4];
#pragma unroll
            for (int kk = 0; kk < 4; ++kk) {
                float4 f0 = pre[2 * kk], f1 = pre[2 * kk + 1];
                union { unsigned u[4]; short8 s8; } cv;
                cv.u[0] = packbf(f0.x, f0.y);
                cv.u[1] = packbf(f0.z, f0.w);
                cv.u[2] = packbf(f1.x, f1.y);
                cv.u[3] = packbf(f1.z, f1.w);
                af[kk] = cv.s8;
            }

            // ---- issue next chunk's cold gathers (drained before fr) ----
            if (c + 4 < total) issuePre(c + 4);

            // ---- GEMM + gate epilogue (shared exp2 + shared rcp) ----
            float pI[4] = {0.f, 0.f, 0.f, 0.f}, pV[4] = {0.f, 0.f, 0.f, 0.f};
#pragma unroll
            for (int nt = 0; nt < 8; ++nt) {
                f32x4 dacc = {0.f, 0.f, 0.f, 0.f};
#pragma unroll
                for (int kk = 0; kk < 4; ++kk)
                    dacc = __builtin_amdgcn_mfma_f32_16x16x32_bf16(
                        af[kk], bfrag[nt * 256 + kk * 64 + lane], dacc, 0, 0, 0);
#pragma unroll
                for (int q = 0; q < 4; ++q) {
                    float t2 = __builtin_amdgcn_exp2f(-dacc[q]);
                    float dI = fmaf(t2, cIr[nt], 1.f);
                    float dV = fmaf(t2, cVr[nt], 1.f);
                    float rr = __builtin_amdgcn_rcpf(dI * dV);
                    pI[q] = fmaf(WeR[nt], dV * rr, pI[q]);   // WeR/dI
                    pV[q] = fmaf(WeR[nt], dI * rr, pV[q]);   // WeR/dV
                }
            }

            // ---- accumulate row-loads (L1-hot: gathers touched the lines;
            //      latency covered by red16 + weight computation below) ----
            const float2* s2 = (const float2*)srcs;
            float2 fr[16];
#pragma unroll
            for (int r = 0; r < 16; ++r) {
                int rr = base + r; if (rr > n - 1) rr = n - 1;
                fr[r] = s2[((size_t)rr << 6) + lane];
            }

            // ---- reduce e across 16 lanes; weights = 2^e directly ----
#pragma unroll
            for (int q = 0; q < 4; ++q) { pI[q] = red16(pI[q]); pV[q] = red16(pV[q]); }
            if (base + 16 > n) {
#pragma unroll
                for (int q = 0; q < 4; ++q) {
                    int r = ((lane >> 4) << 2) + q;
                    if (base + r >= n) { pI[q] = -__builtin_inff(); pV[q] = -__builtin_inff(); }
                }
            }
            float wIq[4], wVq[4];
#pragma unroll
            for (int q = 0; q < 4; ++q) {
                wIq[q] = __builtin_amdgcn_exp2f(pI[q]);   // bounded; 0 if masked
                wVq[q] = __builtin_amdgcn_exp2f(pV[q]);
            }
            lIs += (wIq[0] + wIq[1]) + (wIq[2] + wIq[3]);  // quarter-local
            lVs += (wVq[0] + wVq[1]) + (wVq[2] + wVq[3]);

            // publish weights to per-wave LDS table (same-wave DS ordering)
            if ((lane & 15) == 0) {
                int gq = lane >> 4;
                float4 w0 = {wIq[0], wVq[0], wIq[1], wVq[1]};
                float4 w1 = {wIq[2], wVq[2], wIq[3], wVq[3]};
                *(float4*)&wt[w][gq * 4 + 0][0] = w0;
                *(float4*)&wt[w][gq * 4 + 2][0] = w1;
            }

            // ---- weighted accumulate (pure fma chains, no rescale) ----
#pragma unroll
            for (int r = 0; r < 16; ++r) {
                float2 f = fr[r];
                float2 wv = *(const float2*)&wt[w][r][0];
                aI0 = fmaf(wv.x, f.x, aI0); aI1 = fmaf(wv.x, f.y, aI1);
                aV0 = fmaf(wv.y, f.x, aV0); aV1 = fmaf(wv.y, f.y, aV1);
            }
        }

        // ---- finalize lane-local l: sum the 4 quarters (once per graph) --
        lIs += __shfl_xor(lIs, 16); lIs += __shfl_xor(lIs, 32);
        lVs += __shfl_xor(lVs, 16); lVs += __shfl_xor(lVs, 32);

        // ---- cross-wave combine: plain sums ----
        __syncthreads();   // WAR: previous graph's combine reads done
        {
            float2 vI = {aI0, aI1}, vV = {aV0, aV1};
            *(float2*)&cmbA[0][w][lane * 2] = vI;
            *(float2*)&cmbA[1][w][lane * 2] = vV;
        }
        if (lane == 0) { cmbL[0][w] = lIs; cmbL[1][w] = lVs; }
        __syncthreads();
        {
            int st = t >> 7, d = t & 127;
            float Ls = (cmbL[st][0] + cmbL[st][1]) + (cmbL[st][2] + cmbL[st][3]);
            float A  = (cmbA[st][0][d] + cmbA[st][1][d]) +
                       (cmbA[st][2][d] + cmbA[st][3][d]);
            out[(size_t)st * B * D + (size_t)g * D + d] = A * __builtin_amdgcn_rcpf(Ls);
        }
    }
}

// ---------------------------------------------------------------------------
extern "C" void kernel_launch(void* const* d_in, const int* in_sizes, int n_in,
                              void* d_out, int out_size, void* d_ws, size_t ws_size,
                              hipStream_t stream) {
    const float* xI    = (const float*)d_in[0];
    const float* xV    = (const float*)d_in[1];
    const float* Wu    = (const float*)d_in[2];
    const float* bu    = (const float*)d_in[3];
    const float* Wv    = (const float*)d_in[4];
    const float* We    = (const float*)d_in[5];
    // d_in[6] = seg_ids (unused: segments contiguous, last_nodes suffices)
    const int*   lastn = (const int*)d_in[7];
    const int B = in_sizes[7];               // 8192

    float*  cIb   = (float*)d_ws;
    float*  cVb   = cIb + (size_t)B * D;
    short8* fragW = (short8*)(cVb + (size_t)B * D);

    pack_wu<<<8, 256, 0, stream>>>(Wu, fragW);
    gate_k<<<(B + 15) / 16, 256, 0, stream>>>(xI, xV, Wv, bu, lastn, cIb, cVb, B);
    attn_main<<<B / GPB, 256, 0, stream>>>(xI, xV, We, lastn, cIb, cVb, fragW,
                                           (float*)d_out, B);
}